// Round 1
// baseline (1835.622 us; speedup 1.0000x reference)
//
#include <hip/hip_runtime.h>
#include <stdint.h>
#include <stddef.h>

#define NEGF (-1.0e30f)

typedef __attribute__((ext_vector_type(2))) _Float16 half2_t;

constexpr int Bn = 32;
constexpr int Tn = 2000;
constexpr int Cn = 256;
constexpr int Un = 200;
constexpr int Sn = 2 * Un + 1;  // 401 extended states

// f16 pair dot with fp32 accumulate: c += a.x*b.x + a.y*b.y
__device__ __forceinline__ float fdot2f(uint32_t a, uint32_t b, float c) {
  half2_t ha = __builtin_bit_cast(half2_t, a);
  half2_t hb = __builtin_bit_cast(half2_t, b);
#if __has_builtin(__builtin_amdgcn_fdot2)
  return __builtin_amdgcn_fdot2(ha, hb, c, false);
#else
  return c + (float)ha.x * (float)hb.x + (float)ha.y * (float)hb.y;
#endif
}

__device__ __forceinline__ float wave_max64(float x) {
#pragma unroll
  for (int off = 32; off >= 1; off >>= 1)
    x = fmaxf(x, __shfl_xor(x, off, 64));
  return x;
}

__device__ __forceinline__ float lse3(float a, float b, float c) {
  float m = fmaxf(fmaxf(a, b), c);
  return m + __logf(__expf(a - m) + __expf(b - m) + __expf(c - m));
}

__device__ __forceinline__ int clampi(int v, int lo, int hi) {
  return v < lo ? lo : (v > hi ? hi : v);
}

// 64 blocks x 256 threads. Blocks [0,32): denominator (one b each).
// Blocks [32,64): CTC numerator (one b each). ws[0:32)=num, ws[32:64)=den.
__global__ __launch_bounds__(256, 1) void fwd_kernel(
    const float* __restrict__ logp, const int* __restrict__ targets,
    const int* __restrict__ in_lens, const int* __restrict__ tgt_lens,
    const float* __restrict__ trans, const float* __restrict__ start,
    float* __restrict__ ws) {
  const int tid = threadIdx.x;
  const int bid = blockIdx.x;

  if (bid < Bn) {
    // ================= denominator forward =================
    const int b = bid;
    const int L = clampi(in_lens[b], Sn, Tn);
    const int j = tid;
    const int lane = tid & 63;
    const int wid = tid >> 6;

    __shared__ __align__(16) _Float16 eaH[2][Cn];  // double-buffered exp(alpha - M_seg) in f16
    __shared__ float red[2][4];                    // per-wave (segment) max shifts
    __shared__ float sred[4];

    // E[i][j] = exp(trans[i][j]) for column j, held as 128 f16 pairs in VGPRs.
    // trans ~ N(0,0.1^2)*... -> E in ~[0.55,1.8]: f16-exact to ~5e-4 rel.
    uint32_t Ereg[Cn / 2];
#pragma unroll
    for (int w = 0; w < Cn / 2; ++w) {
      float e0 = __expf(trans[(2 * w) * Cn + j]);
      float e1 = __expf(trans[(2 * w + 1) * Cn + j]);
      half2_t h;
      h.x = (_Float16)e0;
      h.y = (_Float16)e1;
      Ereg[w] = __builtin_bit_cast(uint32_t, h);
    }

    const float* lpb = logp + (size_t)b * Tn * Cn;
    float alpha = start[j] + lpb[j];     // t = 0 (raw logp: lse cancels in num-den)
    float lp_next = lpb[Cn + j];         // prefetch t = 1

    // emit alpha_0 (parity 0): per-wave shift keeps f16 ea well-scaled
    float mw = wave_max64(alpha);
    if (lane == 0) red[0][wid] = mw;
    eaH[0][j] = (_Float16)__expf(alpha - mw);
    __syncthreads();

    for (int t = 1; t < L; ++t) {
      const int pr = (t - 1) & 1, pw = t & 1;
      const float lp_cur = lp_next;
      const int tnext = (t + 1 < L) ? t + 1 : L - 1;
      lp_next = lpb[(size_t)tnext * Cn + j];  // software prefetch next frame

      // s_j = sum_i ea[i] * E[i][j], 4 independent segment accumulators
      const uint4* eap = (const uint4*)(eaH[pr]);
      float a0 = 0.f, a1 = 0.f, a2 = 0.f, a3 = 0.f;
#pragma unroll
      for (int i8 = 0; i8 < 8; ++i8) {
        uint4 q0 = eap[i8];        // seg0: i in [  0, 64)
        uint4 q1 = eap[8 + i8];    // seg1: i in [ 64,128)
        uint4 q2 = eap[16 + i8];   // seg2: i in [128,192)
        uint4 q3 = eap[24 + i8];   // seg3: i in [192,256)
        a0 = fdot2f(Ereg[4 * i8 + 0], q0.x, a0);
        a0 = fdot2f(Ereg[4 * i8 + 1], q0.y, a0);
        a0 = fdot2f(Ereg[4 * i8 + 2], q0.z, a0);
        a0 = fdot2f(Ereg[4 * i8 + 3], q0.w, a0);
        a1 = fdot2f(Ereg[32 + 4 * i8 + 0], q1.x, a1);
        a1 = fdot2f(Ereg[32 + 4 * i8 + 1], q1.y, a1);
        a1 = fdot2f(Ereg[32 + 4 * i8 + 2], q1.z, a1);
        a1 = fdot2f(Ereg[32 + 4 * i8 + 3], q1.w, a1);
        a2 = fdot2f(Ereg[64 + 4 * i8 + 0], q2.x, a2);
        a2 = fdot2f(Ereg[64 + 4 * i8 + 1], q2.y, a2);
        a2 = fdot2f(Ereg[64 + 4 * i8 + 2], q2.z, a2);
        a2 = fdot2f(Ereg[64 + 4 * i8 + 3], q2.w, a2);
        a3 = fdot2f(Ereg[96 + 4 * i8 + 0], q3.x, a3);
        a3 = fdot2f(Ereg[96 + 4 * i8 + 1], q3.y, a3);
        a3 = fdot2f(Ereg[96 + 4 * i8 + 2], q3.z, a3);
        a3 = fdot2f(Ereg[96 + 4 * i8 + 3], q3.w, a3);
      }
      // combine segments with their shifts (fp32)
      const float M0 = red[pr][0], M1 = red[pr][1];
      const float M2 = red[pr][2], M3 = red[pr][3];
      const float M = fmaxf(fmaxf(M0, M1), fmaxf(M2, M3));
      const float s = __expf(M0 - M) * a0 + __expf(M1 - M) * a1 +
                      __expf(M2 - M) * a2 + __expf(M3 - M) * a3;
      alpha = M + __logf(s) + lp_cur;

      mw = wave_max64(alpha);
      if (lane == 0) red[pw][wid] = mw;
      eaH[pw][j] = (_Float16)__expf(alpha - mw);
      __syncthreads();
    }

    // den[b] = logsumexp_j alpha_j
    {
      const int pL = (L - 1) & 1;
      const float M0 = red[pL][0], M1 = red[pL][1];
      const float M2 = red[pL][2], M3 = red[pL][3];
      const float M = fmaxf(fmaxf(M0, M1), fmaxf(M2, M3));
      float e = __expf(alpha - M);
#pragma unroll
      for (int off = 32; off >= 1; off >>= 1) e += __shfl_xor(e, off, 64);
      if (lane == 0) sred[wid] = e;
      __syncthreads();
      if (tid == 0) {
        float ssum = (sred[0] + sred[1]) + (sred[2] + sred[3]);
        ws[Bn + b] = M + __logf(ssum);
      }
    }
  } else {
    // ================= CTC numerator forward =================
    const int b = bid - Bn;
    const int L = clampi(in_lens[b], Sn, Tn);
    const int tl = clampi(tgt_lens[b], 1, Un);

    __shared__ float abuf[2][Sn + 3];  // +2 front pad (NEG), states at [s+2]
    const float* lpb = logp + (size_t)b * Tn * Cn;
    const int* tgtb = targets + b * Un;

    const int s1 = tid;         // states 0..255
    const int s2 = tid + 256;   // states 256..400 (valid if < Sn)
    int e1 = 0, e2 = 0;
    bool k1 = false, k2 = false;
    if (s1 & 1) {
      const int u = (s1 - 1) >> 1;
      e1 = clampi(tgtb[u], 1, Cn - 1);
      if (u > 0) k1 = (e1 != clampi(tgtb[u - 1], 1, Cn - 1));
    }
    if ((s2 < Sn) && (s2 & 1)) {
      const int u = (s2 - 1) >> 1;
      e2 = clampi(tgtb[u], 1, Cn - 1);
      k2 = (e2 != clampi(tgtb[u - 1], 1, Cn - 1));  // u >= 127 > 0 here
    }

    // t = 0 init
    abuf[0][s1 + 2] = (s1 == 0) ? lpb[0] : (s1 == 1 ? lpb[e1] : NEGF);
    if (s2 < Sn) abuf[0][s2 + 2] = NEGF;
    if (tid < 2) { abuf[0][tid] = NEGF; abuf[1][tid] = NEGF; }
    float pe1 = lpb[Cn + e1];   // prefetch emissions for t=1 (addresses t-invariant)
    float pe2 = lpb[Cn + e2];
    __syncthreads();

    int cur = 0;
    for (int t = 1; t < L; ++t) {
      const float em1 = pe1, em2 = pe2;
      const int tnext = (t + 1 < L) ? t + 1 : L - 1;
      pe1 = lpb[(size_t)tnext * Cn + e1];
      pe2 = lpb[(size_t)tnext * Cn + e2];
      const float* A = abuf[cur];
      float* Bv = abuf[cur ^ 1];
      {
        const float x = A[s1 + 2], y = A[s1 + 1];
        const float z = k1 ? A[s1] : NEGF;
        Bv[s1 + 2] = lse3(x, y, z) + em1;
      }
      if (s2 < Sn) {
        const float x = A[s2 + 2], y = A[s2 + 1];
        const float z = k2 ? A[s2] : NEGF;
        Bv[s2 + 2] = lse3(x, y, z) + em2;
      }
      __syncthreads();
      cur ^= 1;
    }
    if (tid == 0) {
      const int l = 2 * tl;
      const float x = abuf[cur][l + 2], y = abuf[cur][l + 1];
      const float m = fmaxf(x, y);
      ws[b] = m + __logf(__expf(x - m) + __expf(y - m));
    }
  }
}

__global__ void finalize_kernel(const float* __restrict__ ws,
                                float* __restrict__ out) {
  const int tid = threadIdx.x;  // 64 threads, one wave
  float tot = 0.f, cnt = 0.f;
  if (tid < Bn) {
    const float tv = ws[tid] - ws[Bn + tid];   // num - DEN_SCALE*den
    const bool valid = tv > 0.5f * NEGF;
    tot = valid ? tv : 0.f;
    cnt = valid ? 1.f : 0.f;
  }
#pragma unroll
  for (int off = 32; off >= 1; off >>= 1) {
    tot += __shfl_xor(tot, off, 64);
    cnt += __shfl_xor(cnt, off, 64);
  }
  if (tid == 0) out[0] = -tot / fmaxf(cnt, 1.f);
}

extern "C" void kernel_launch(void* const* d_in, const int* in_sizes, int n_in,
                              void* d_out, int out_size, void* d_ws, size_t ws_size,
                              hipStream_t stream) {
  const float* logp = (const float*)d_in[0];
  const int* targets = (const int*)d_in[1];
  const int* in_lens = (const int*)d_in[2];
  const int* tgt_lens = (const int*)d_in[3];
  const float* trans = (const float*)d_in[4];
  const float* start = (const float*)d_in[5];
  float* ws = (float*)d_ws;
  float* out = (float*)d_out;
  (void)in_sizes; (void)n_in; (void)out_size; (void)ws_size;

  fwd_kernel<<<dim3(2 * Bn), dim3(256), 0, stream>>>(
      logp, targets, in_lens, tgt_lens, trans, start, ws);
  finalize_kernel<<<dim3(1), dim3(64), 0, stream>>>(ws, out);
}

// Round 2
// 1221.702 us; speedup vs baseline: 1.5025x; 1.5025x over previous
//
#include <hip/hip_runtime.h>
#include <stdint.h>
#include <stddef.h>

#define NEGF (-1.0e30f)

typedef __attribute__((ext_vector_type(2))) _Float16 half2_t;

constexpr int Bn = 32;
constexpr int Tn = 2000;
constexpr int Cn = 256;
constexpr int Un = 200;
constexpr int Sn = 2 * Un + 1;  // 401 extended states
constexpr float Kn = 4096.0f;   // den normalization target (Sigma stored ~ K)

// f16 pair dot with fp32 accumulate: c += a.x*b.x + a.y*b.y
__device__ __forceinline__ float fdot2f(uint32_t a, uint32_t b, float c) {
  half2_t ha = __builtin_bit_cast(half2_t, a);
  half2_t hb = __builtin_bit_cast(half2_t, b);
#if __has_builtin(__builtin_amdgcn_fdot2)
  return __builtin_amdgcn_fdot2(ha, hb, c, false);
#else
  return c + (float)ha.x * (float)hb.x + (float)ha.y * (float)hb.y;
#endif
}

// Sum across the 4 lanes of an aligned quad (lanes 4u..4u+3); all lanes get it.
__device__ __forceinline__ float quad_sum(float x) {
#if __has_builtin(__builtin_amdgcn_update_dpp)
  int xi = __builtin_bit_cast(int, x);
  int y = __builtin_amdgcn_update_dpp(0, xi, 0xB1, 0xF, 0xF, false);  // quad_perm(1,0,3,2)
  float s = x + __builtin_bit_cast(float, y);
  int si = __builtin_bit_cast(int, s);
  int z = __builtin_amdgcn_update_dpp(0, si, 0x4E, 0xF, 0xF, false);  // quad_perm(2,3,0,1)
  return s + __builtin_bit_cast(float, z);
#else
  x += __shfl_xor(x, 1, 64);
  x += __shfl_xor(x, 2, 64);
  return x;
#endif
}

__device__ __forceinline__ float lse3(float a, float b, float c) {
  float m = fmaxf(fmaxf(a, b), c);
  return m + __logf(__expf(a - m) + __expf(b - m) + __expf(c - m));
}

__device__ __forceinline__ int clampi(int v, int lo, int hi) {
  return v < lo ? lo : (v > hi ? hi : v);
}

// 64 blocks x 256 threads. Blocks [0,32): denominator. Blocks [32,64): CTC num.
// waves_per_eu(1,1): pins 1 wave/SIMD -> 512-VGPR budget so the 128-reg E tile
// NEVER spills (round-1: VGPR=160 + 32GB FETCH_SIZE = scratch-spill thrash).
__global__ __launch_bounds__(256)
__attribute__((amdgpu_waves_per_eu(1, 1)))
void fwd_kernel(
    const float* __restrict__ logp, const int* __restrict__ targets,
    const int* __restrict__ in_lens, const int* __restrict__ tgt_lens,
    const float* __restrict__ trans, const float* __restrict__ start,
    float* __restrict__ ws) {
  const int tid = threadIdx.x;
  const int bid = blockIdx.x;

  if (bid < Bn) {
    // ================= denominator forward (exp domain) =================
    // thread (u,q): q=tid&3 (i-chunk [64q,64q+64)), u=tid>>2; owns column jw=u+64q.
    // Holds E[i][j] f16 pairs for its i-chunk x 4 columns {u+64k} in 128 VGPRs.
    // Per step: s_jk partials over own chunk -> quad DPP reduce over q -> full s;
    // normalize by Z=Sigma(ea) (also quad-reduced), write ea'_jw = s*p*K/Z to LDS.
    const int b = bid;
    const int L = clampi(in_lens[b], Sn, Tn);
    const int q = tid & 3;
    const int u = tid >> 2;
    const int jw = u + 64 * q;

    __shared__ __align__(16) _Float16 eaH[2][Cn];  // double-buffered scaled-exp alpha
    __shared__ float sred[4];

    // E tile: Ereg[k][m] = (exp(trans[64q+2m][u+64k]), exp(trans[64q+2m+1][u+64k]))
    uint32_t Ereg[4][32];
#pragma unroll
    for (int k = 0; k < 4; ++k) {
      const int jk = u + 64 * k;
#pragma unroll
      for (int m = 0; m < 32; ++m) {
        const int i0 = 64 * q + 2 * m;
        float e0 = __expf(trans[i0 * Cn + jk]);
        float e1 = __expf(trans[(i0 + 1) * Cn + jk]);
        half2_t h;
        h.x = (_Float16)e0;
        h.y = (_Float16)e1;
        Ereg[k][m] = __builtin_bit_cast(uint32_t, h);
      }
    }

    const float* lpb = logp + (size_t)b * Tn * Cn;

    // t = 0 init: stored = K * exp(start + lp0)  (raw logp: lse cancels num-den)
    float G = -__logf(Kn);  // log-scale carried out of the stored values
    eaH[0][jw] = (_Float16)(Kn * __expf(start[jw] + lpb[jw]));
    float lp_next = lpb[Cn + jw];  // prefetch t = 1
    __syncthreads();

    const uint32_t ONE2 = 0x3C003C00u;  // f16 (1.0, 1.0)

    for (int t = 1; t < L; ++t) {
      const int pr = (t - 1) & 1, pw = t & 1;
      const float lp_cur = lp_next;
      const int tnext = (t + 1 < L) ? t + 1 : L - 1;
      lp_next = lpb[(size_t)tnext * Cn + jw];  // software prefetch next frame
      const float p = __expf(lp_cur);          // off critical chain

      const uint4* eap = (const uint4*)(&eaH[pr][64 * q]);  // own 128B chunk
      float a0 = 0.f, a1 = 0.f, a2 = 0.f, a3 = 0.f, zz = 0.f;
#pragma unroll
      for (int m4 = 0; m4 < 8; ++m4) {
        const uint4 e4 = eap[m4];
        a0 = fdot2f(Ereg[0][4 * m4 + 0], e4.x, a0);
        a0 = fdot2f(Ereg[0][4 * m4 + 1], e4.y, a0);
        a0 = fdot2f(Ereg[0][4 * m4 + 2], e4.z, a0);
        a0 = fdot2f(Ereg[0][4 * m4 + 3], e4.w, a0);
        a1 = fdot2f(Ereg[1][4 * m4 + 0], e4.x, a1);
        a1 = fdot2f(Ereg[1][4 * m4 + 1], e4.y, a1);
        a1 = fdot2f(Ereg[1][4 * m4 + 2], e4.z, a1);
        a1 = fdot2f(Ereg[1][4 * m4 + 3], e4.w, a1);
        a2 = fdot2f(Ereg[2][4 * m4 + 0], e4.x, a2);
        a2 = fdot2f(Ereg[2][4 * m4 + 1], e4.y, a2);
        a2 = fdot2f(Ereg[2][4 * m4 + 2], e4.z, a2);
        a2 = fdot2f(Ereg[2][4 * m4 + 3], e4.w, a2);
        a3 = fdot2f(Ereg[3][4 * m4 + 0], e4.x, a3);
        a3 = fdot2f(Ereg[3][4 * m4 + 1], e4.y, a3);
        a3 = fdot2f(Ereg[3][4 * m4 + 2], e4.z, a3);
        a3 = fdot2f(Ereg[3][4 * m4 + 3], e4.w, a3);
        zz = fdot2f(ONE2, e4.x, zz);
        zz = fdot2f(ONE2, e4.y, zz);
        zz = fdot2f(ONE2, e4.z, zz);
        zz = fdot2f(ONE2, e4.w, zz);
      }
      // combine i-chunks across the quad (q = lane&3): 2 DPP adds each
      a0 = quad_sum(a0);
      a1 = quad_sum(a1);
      a2 = quad_sum(a2);
      a3 = quad_sum(a3);
      zz = quad_sum(zz);  // Z = Sigma_i ea_i, uniform across block

      const float s = (q == 0) ? a0 : (q == 1) ? a1 : (q == 2) ? a2 : a3;
      const float invZ = Kn * __frcp_rn(zz);  // exact self-consistency via G below
      G -= __logf(invZ);
      eaH[pw][jw] = (_Float16)(s * p * invZ);
      __syncthreads();
    }

    // den[b] = G + log(Sigma_j stored_j)
    {
      const int pL = (L - 1) & 1;
      float e = (float)eaH[pL][tid];
#pragma unroll
      for (int off = 32; off >= 1; off >>= 1) e += __shfl_xor(e, off, 64);
      const int lane = tid & 63, wid = tid >> 6;
      if (lane == 0) sred[wid] = e;
      __syncthreads();
      if (tid == 0) {
        float ssum = (sred[0] + sred[1]) + (sred[2] + sred[3]);
        ws[Bn + b] = G + __logf(ssum);
      }
    }
  } else {
    // ================= CTC numerator forward (log domain) =================
    const int b = bid - Bn;
    const int L = clampi(in_lens[b], Sn, Tn);
    const int tl = clampi(tgt_lens[b], 1, Un);

    __shared__ float abuf[2][Sn + 3];  // +2 front pad (NEG), states at [s+2]
    const float* lpb = logp + (size_t)b * Tn * Cn;
    const int* tgtb = targets + b * Un;

    const int s1 = tid;        // states 0..255
    const int s2 = tid + 256;  // states 256..400 (valid if < Sn)
    int e1 = 0, e2 = 0;
    bool k1 = false, k2 = false;
    if (s1 & 1) {
      const int uu = (s1 - 1) >> 1;
      e1 = clampi(tgtb[uu], 1, Cn - 1);
      if (uu > 0) k1 = (e1 != clampi(tgtb[uu - 1], 1, Cn - 1));
    }
    if ((s2 < Sn) && (s2 & 1)) {
      const int uu = (s2 - 1) >> 1;
      e2 = clampi(tgtb[uu], 1, Cn - 1);
      k2 = (e2 != clampi(tgtb[uu - 1], 1, Cn - 1));  // uu >= 127 > 0 here
    }

    // t = 0 init
    abuf[0][s1 + 2] = (s1 == 0) ? lpb[0] : (s1 == 1 ? lpb[e1] : NEGF);
    if (s2 < Sn) abuf[0][s2 + 2] = NEGF;
    if (tid < 2) { abuf[0][tid] = NEGF; abuf[1][tid] = NEGF; }
    float pe1 = lpb[Cn + e1];  // prefetch emissions for t=1 (addresses t-invariant)
    float pe2 = lpb[Cn + e2];
    __syncthreads();

    int cur = 0;
    for (int t = 1; t < L; ++t) {
      const float em1 = pe1, em2 = pe2;
      const int tnext = (t + 1 < L) ? t + 1 : L - 1;
      pe1 = lpb[(size_t)tnext * Cn + e1];
      pe2 = lpb[(size_t)tnext * Cn + e2];
      const float* A = abuf[cur];
      float* Bv = abuf[cur ^ 1];
      {
        const float x = A[s1 + 2], y = A[s1 + 1];
        const float z = k1 ? A[s1] : NEGF;
        Bv[s1 + 2] = lse3(x, y, z) + em1;
      }
      if (s2 < Sn) {
        const float x = A[s2 + 2], y = A[s2 + 1];
        const float z = k2 ? A[s2] : NEGF;
        Bv[s2 + 2] = lse3(x, y, z) + em2;
      }
      __syncthreads();
      cur ^= 1;
    }
    if (tid == 0) {
      const int l = 2 * tl;
      const float x = abuf[cur][l + 2], y = abuf[cur][l + 1];
      const float m = fmaxf(x, y);
      ws[b] = m + __logf(__expf(x - m) + __expf(y - m));
    }
  }
}

__global__ void finalize_kernel(const float* __restrict__ ws,
                                float* __restrict__ out) {
  const int tid = threadIdx.x;  // 64 threads, one wave
  float tot = 0.f, cnt = 0.f;
  if (tid < Bn) {
    const float tv = ws[tid] - ws[Bn + tid];  // num - DEN_SCALE*den
    const bool valid = tv > 0.5f * NEGF;
    tot = valid ? tv : 0.f;
    cnt = valid ? 1.f : 0.f;
  }
#pragma unroll
  for (int off = 32; off >= 1; off >>= 1) {
    tot += __shfl_xor(tot, off, 64);
    cnt += __shfl_xor(cnt, off, 64);
  }
  if (tid == 0) out[0] = -tot / fmaxf(cnt, 1.f);
}

extern "C" void kernel_launch(void* const* d_in, const int* in_sizes, int n_in,
                              void* d_out, int out_size, void* d_ws, size_t ws_size,
                              hipStream_t stream) {
  const float* logp = (const float*)d_in[0];
  const int* targets = (const int*)d_in[1];
  const int* in_lens = (const int*)d_in[2];
  const int* tgt_lens = (const int*)d_in[3];
  const float* trans = (const float*)d_in[4];
  const float* start = (const float*)d_in[5];
  float* ws = (float*)d_ws;
  float* out = (float*)d_out;
  (void)in_sizes; (void)n_in; (void)out_size; (void)ws_size;

  fwd_kernel<<<dim3(2 * Bn), dim3(256), 0, stream>>>(
      logp, targets, in_lens, tgt_lens, trans, start, ws);
  finalize_kernel<<<dim3(1), dim3(64), 0, stream>>>(ws, out);
}

// Round 3
// 1133.851 us; speedup vs baseline: 1.6189x; 1.0775x over previous
//
#include <hip/hip_runtime.h>
#include <stdint.h>
#include <stddef.h>

#define NEGF (-1.0e30f)

typedef __attribute__((ext_vector_type(2))) _Float16 half2_t;
typedef uint32_t u32x16 __attribute__((ext_vector_type(16)));

constexpr int Bn = 32;
constexpr int Tn = 2000;
constexpr int Cn = 256;
constexpr int Un = 200;
constexpr int Sn = 2 * Un + 1;  // 401 extended states
constexpr float Kn = 4096.0f;   // den normalization target

// f16 pair dot with fp32 accumulate: c += a.x*b.x + a.y*b.y
__device__ __forceinline__ float fdot2f(uint32_t a, uint32_t b, float c) {
  half2_t ha = __builtin_bit_cast(half2_t, a);
  half2_t hb = __builtin_bit_cast(half2_t, b);
#if __has_builtin(__builtin_amdgcn_fdot2)
  return __builtin_amdgcn_fdot2(ha, hb, c, false);
#else
  return c + (float)ha.x * (float)hb.x + (float)ha.y * (float)hb.y;
#endif
}

template <int CTRL>
__device__ __forceinline__ float dppf(float x) {
#if __has_builtin(__builtin_amdgcn_update_dpp)
  int xi = __builtin_bit_cast(int, x);
  int y = __builtin_amdgcn_update_dpp(0, xi, CTRL, 0xF, 0xF, false);
  return __builtin_bit_cast(float, y);
#else
  return x;
#endif
}
#define dpp_x1(v) dppf<0xB1>(v)   // quad_perm(1,0,3,2): lane ^ 1
#define dpp_x2(v) dppf<0x4E>(v)   // quad_perm(2,3,0,1): lane ^ 2
#define dpp_x7(v) dppf<0x141>(v)  // row_half_mirror:    lane ^ 7

__device__ __forceinline__ uint32_t packe(float a, float b) {
  half2_t h;
  h.x = (_Float16)a;
  h.y = (_Float16)b;
  return __builtin_bit_cast(uint32_t, h);
}

__device__ __forceinline__ float lse3(float a, float b, float c) {
  float m = fmaxf(fmaxf(a, b), c);
  return m + __logf(__expf(a - m) + __expf(b - m) + __expf(c - m));
}

__device__ __forceinline__ int clampi(int v, int lo, int hi) {
  return v < lo ? lo : (v > hi ? hi : v);
}

// 64 blocks x 256 threads. Blocks [0,32): denominator. Blocks [32,64): CTC num.
__global__ __launch_bounds__(256)
__attribute__((amdgpu_waves_per_eu(1, 1)))
void fwd_kernel(
    const float* __restrict__ logp, const int* __restrict__ targets,
    const int* __restrict__ in_lens, const int* __restrict__ tgt_lens,
    const float* __restrict__ trans, const float* __restrict__ start,
    float* __restrict__ ws) {
  const int tid = threadIdx.x;
  const int bid = blockIdx.x;

  if (bid < Bn) {
    // ============ denominator forward, exp domain, 32i x 8col tile ============
    // q = tid&7: i-chunk [32q,32q+32). u = tid>>3 in [0,32): columns {u+32k}.
    // E held as 8 ext_vector(16) SSA values (128 VGPRs) -> cannot spill via SROA
    // failure (round-2 root cause: 128-elt array stayed in scratch, VGPR=132).
    const int b = bid;
    const int L = clampi(in_lens[b], Sn, Tn);
    const int q = tid & 7;
    const int u = tid >> 3;
    const int jw = u + 32 * q;  // column this lane owns after the reduce

    // ea chunks at 80B stride: banks (20q+4m)%32 = perfect 32-bank permutation
    // per ds_read_b128 (round-2: 128B stride -> 4-way conflict, 7.2M counts).
    __shared__ __align__(16) char eaLDS[2 * 8 * 80];
    __shared__ float sred[4];

    const float* trow = trans;
#define EP(c, m) packe(__expf(trow[(32 * q + 2 * (m)) * Cn + (c)]), \
                       __expf(trow[(32 * q + 2 * (m) + 1) * Cn + (c)]))
#define MKCOL(c)                                                          \
  (u32x16){EP(c, 0),  EP(c, 1),  EP(c, 2),  EP(c, 3),  EP(c, 4),          \
           EP(c, 5),  EP(c, 6),  EP(c, 7),  EP(c, 8),  EP(c, 9),          \
           EP(c, 10), EP(c, 11), EP(c, 12), EP(c, 13), EP(c, 14), EP(c, 15)}
    u32x16 E0 = MKCOL(u + 0);
    u32x16 E1 = MKCOL(u + 32);
    u32x16 E2 = MKCOL(u + 64);
    u32x16 E3 = MKCOL(u + 96);
    u32x16 E4 = MKCOL(u + 128);
    u32x16 E5 = MKCOL(u + 160);
    u32x16 E6 = MKCOL(u + 192);
    u32x16 E7 = MKCOL(u + 224);
#undef MKCOL
#undef EP

    const float* lpb = logp + (size_t)b * Tn * Cn;
    const char* rbase0 = eaLDS + 80 * q;              // this lane's read chunk
    char* wptr0 = eaLDS + 80 * q + 2 * u;             // this lane's write slot

    // t = 0: stored = K * exp(start + lp0); G carries the log scale.
    float G = -__logf(Kn);
    *(_Float16*)(wptr0) = (_Float16)(Kn * __expf(start[jw] + lpb[jw]));
    float lp_next = lpb[Cn + jw];
    __syncthreads();

    const uint32_t ONE2 = 0x3C003C00u;  // f16 (1.0, 1.0)
    const bool q4 = (q & 4) != 0, q2 = (q & 2) != 0, q1 = (q & 1) != 0;

    for (int t = 1; t < L; ++t) {
      const int pr = (t - 1) & 1, pw = t & 1;
      const float lp_cur = lp_next;
      const int tnext = (t + 1 < L) ? t + 1 : L - 1;
      lp_next = lpb[(size_t)tnext * Cn + jw];  // prefetch next frame
      const float p = __expf(lp_cur);

      const uint4* eap = (const uint4*)(rbase0 + pr * 640);
      float a0 = 0.f, a1 = 0.f, a2 = 0.f, a3 = 0.f;
      float a4 = 0.f, a5 = 0.f, a6 = 0.f, a7 = 0.f;
      half2_t zpk = {(_Float16)0.f, (_Float16)0.f};
#define B2(x) __builtin_bit_cast(half2_t, x)
#define DOT8(idx, ev)               \
  a0 = fdot2f(E0[idx], ev, a0);     \
  a1 = fdot2f(E1[idx], ev, a1);     \
  a2 = fdot2f(E2[idx], ev, a2);     \
  a3 = fdot2f(E3[idx], ev, a3);     \
  a4 = fdot2f(E4[idx], ev, a4);     \
  a5 = fdot2f(E5[idx], ev, a5);     \
  a6 = fdot2f(E6[idx], ev, a6);     \
  a7 = fdot2f(E7[idx], ev, a7);
#define DOTQ(m4)                                                      \
  {                                                                   \
    const uint4 e4 = eap[m4];                                         \
    DOT8(4 * (m4) + 0, e4.x)                                          \
    DOT8(4 * (m4) + 1, e4.y)                                          \
    DOT8(4 * (m4) + 2, e4.z)                                          \
    DOT8(4 * (m4) + 3, e4.w)                                          \
    zpk = zpk + ((B2(e4.x) + B2(e4.y)) + (B2(e4.z) + B2(e4.w)));      \
  }
      DOTQ(0)
      DOTQ(1)
      DOTQ(2)
      DOTQ(3)
#undef DOTQ
#undef DOT8

      // Z = Sigma_i ea_i: chunk sum (f16 pairs) -> 8-lane DPP butterfly
      float zc = fdot2f(ONE2, __builtin_bit_cast(uint32_t, zpk), 0.f);
      zc += dpp_x1(zc);
      zc += dpp_x2(zc);
      zc += dpp_x7(zc);  // all 8 lanes of the q-group now hold Z (block-uniform)

      // column reduce over the 8-lane q-group: give/keep halving exchange.
      // stage 1 (partner q^7, split by bit2), stage 2 (q^2, bit1), stage 3 (q^1, bit0)
      float g, t0, t1, t2, t3, w0, w1, s;
      g = q4 ? a0 : a4;  t0 = (q4 ? a4 : a0) + dpp_x7(g);
      g = q4 ? a1 : a5;  t1 = (q4 ? a5 : a1) + dpp_x7(g);
      g = q4 ? a2 : a6;  t2 = (q4 ? a6 : a2) + dpp_x7(g);
      g = q4 ? a3 : a7;  t3 = (q4 ? a7 : a3) + dpp_x7(g);
      g = q2 ? t0 : t2;  w0 = (q2 ? t2 : t0) + dpp_x2(g);
      g = q2 ? t1 : t3;  w1 = (q2 ? t3 : t1) + dpp_x2(g);
      g = q1 ? w0 : w1;  s  = (q1 ? w1 : w0) + dpp_x1(g);
      // lane (u,q) now holds full s for column u+32q = jw

      const float invZ = Kn * __frcp_rn(zc);
      G -= __logf(invZ);
      *(_Float16*)(wptr0 + pw * 640) = (_Float16)(s * p * invZ);
      __syncthreads();
    }

    // den[b] = G + log(Sigma_j stored_j)
    {
      const int pL = (L - 1) & 1;
      const char* fb = eaLDS + pL * 640;
      float e = (float)(*(const _Float16*)(fb + 80 * (tid >> 5) + 2 * (tid & 31)));
#pragma unroll
      for (int off = 32; off >= 1; off >>= 1) e += __shfl_xor(e, off, 64);
      const int lane = tid & 63, wid = tid >> 6;
      if (lane == 0) sred[wid] = e;
      __syncthreads();
      if (tid == 0) {
        float ssum = (sred[0] + sred[1]) + (sred[2] + sred[3]);
        ws[Bn + b] = G + __logf(ssum);
      }
    }
  } else {
    // ================= CTC numerator forward (log domain) =================
    const int b = bid - Bn;
    const int L = clampi(in_lens[b], Sn, Tn);
    const int tl = clampi(tgt_lens[b], 1, Un);

    __shared__ float abuf[2][Sn + 3];  // +2 front pad (NEG), states at [s+2]
    const float* lpb = logp + (size_t)b * Tn * Cn;
    const int* tgtb = targets + b * Un;

    const int s1 = tid;        // states 0..255
    const int s2 = tid + 256;  // states 256..400 (valid if < Sn)
    int e1 = 0, e2 = 0;
    bool k1 = false, k2 = false;
    if (s1 & 1) {
      const int uu = (s1 - 1) >> 1;
      e1 = clampi(tgtb[uu], 1, Cn - 1);
      if (uu > 0) k1 = (e1 != clampi(tgtb[uu - 1], 1, Cn - 1));
    }
    if ((s2 < Sn) && (s2 & 1)) {
      const int uu = (s2 - 1) >> 1;
      e2 = clampi(tgtb[uu], 1, Cn - 1);
      k2 = (e2 != clampi(tgtb[uu - 1], 1, Cn - 1));  // uu >= 127 > 0 here
    }

    // t = 0 init
    abuf[0][s1 + 2] = (s1 == 0) ? lpb[0] : (s1 == 1 ? lpb[e1] : NEGF);
    if (s2 < Sn) abuf[0][s2 + 2] = NEGF;
    if (tid < 2) { abuf[0][tid] = NEGF; abuf[1][tid] = NEGF; }
    float pe1 = lpb[Cn + e1];  // prefetch emissions (addresses t-invariant)
    float pe2 = lpb[Cn + e2];
    __syncthreads();

    int cur = 0;
    for (int t = 1; t < L; ++t) {
      const float em1 = pe1, em2 = pe2;
      const int tnext = (t + 1 < L) ? t + 1 : L - 1;
      pe1 = lpb[(size_t)tnext * Cn + e1];
      pe2 = lpb[(size_t)tnext * Cn + e2];
      const float* A = abuf[cur];
      float* Bv = abuf[cur ^ 1];
      {
        const float x = A[s1 + 2], y = A[s1 + 1];
        const float z = k1 ? A[s1] : NEGF;
        Bv[s1 + 2] = lse3(x, y, z) + em1;
      }
      if (s2 < Sn) {
        const float x = A[s2 + 2], y = A[s2 + 1];
        const float z = k2 ? A[s2] : NEGF;
        Bv[s2 + 2] = lse3(x, y, z) + em2;
      }
      __syncthreads();
      cur ^= 1;
    }
    if (tid == 0) {
      const int l = 2 * tl;
      const float x = abuf[cur][l + 2], y = abuf[cur][l + 1];
      const float m = fmaxf(x, y);
      ws[b] = m + __logf(__expf(x - m) + __expf(y - m));
    }
  }
}

__global__ void finalize_kernel(const float* __restrict__ ws,
                                float* __restrict__ out) {
  const int tid = threadIdx.x;  // 64 threads, one wave
  float tot = 0.f, cnt = 0.f;
  if (tid < Bn) {
    const float tv = ws[tid] - ws[Bn + tid];  // num - DEN_SCALE*den
    const bool valid = tv > 0.5f * NEGF;
    tot = valid ? tv : 0.f;
    cnt = valid ? 1.f : 0.f;
  }
#pragma unroll
  for (int off = 32; off >= 1; off >>= 1) {
    tot += __shfl_xor(tot, off, 64);
    cnt += __shfl_xor(cnt, off, 64);
  }
  if (tid == 0) out[0] = -tot / fmaxf(cnt, 1.f);
}

extern "C" void kernel_launch(void* const* d_in, const int* in_sizes, int n_in,
                              void* d_out, int out_size, void* d_ws, size_t ws_size,
                              hipStream_t stream) {
  const float* logp = (const float*)d_in[0];
  const int* targets = (const int*)d_in[1];
  const int* in_lens = (const int*)d_in[2];
  const int* tgt_lens = (const int*)d_in[3];
  const float* trans = (const float*)d_in[4];
  const float* start = (const float*)d_in[5];
  float* ws = (float*)d_ws;
  float* out = (float*)d_out;
  (void)in_sizes; (void)n_in; (void)out_size; (void)ws_size;

  fwd_kernel<<<dim3(2 * Bn), dim3(256), 0, stream>>>(
      logp, targets, in_lens, tgt_lens, trans, start, ws);
  finalize_kernel<<<dim3(1), dim3(64), 0, stream>>>(ws, out);
}